// Round 1
// baseline (28036.356 us; speedup 1.0000x reference)
//
#include <hip/hip_runtime.h>
#include <math.h>

// Problem constants (from reference)
static const int NB   = 32;     // batch
static const int NT   = 2000;   // timesteps
static const int NFIN = 256;    // input features
static const int NH   = 1024;   // hidden
static const int NOUT = 256;    // output
static const int KCOMB = NH + NFIN;  // 1280: [r | x] concatenated K
static const int ASTR  = 1280;       // LDS row stride for A (multiple of 4)

// ---------------------------------------------------------------------------
// Wcomb[k][j], k in [0,1280), j in [0,1024):
//   k <  1024 : G*Wr[k][j] + sum_o Wo[k][o]*Wf[o][j]   (Weff)
//   k >= 1024 : Wi[k-1024][j]
// ---------------------------------------------------------------------------
__global__ __launch_bounds__(256) void init_wcomb(
    const float* __restrict__ Wr, const float* __restrict__ Wi,
    const float* __restrict__ Wf, const float* __restrict__ Wo,
    float* __restrict__ Wcomb)
{
    __shared__ float wo_s[NOUT];
    const int row = blockIdx.x;
    const int tid = threadIdx.x;
    if (row < NH) {
        wo_s[tid] = Wo[row * NOUT + tid];
        __syncthreads();
        float acc[4];
#pragma unroll
        for (int jj = 0; jj < 4; ++jj)
            acc[jj] = 1.2f * Wr[row * NH + jj * 256 + tid];
        for (int o = 0; o < NOUT; ++o) {
            const float w = wo_s[o];
#pragma unroll
            for (int jj = 0; jj < 4; ++jj)
                acc[jj] = fmaf(w, Wf[o * NH + jj * 256 + tid], acc[jj]);
        }
#pragma unroll
        for (int jj = 0; jj < 4; ++jj)
            Wcomb[row * NH + jj * 256 + tid] = acc[jj];
    } else {
        const int r2 = row - NH;
#pragma unroll
        for (int jj = 0; jj < 4; ++jj)
            Wcomb[row * NH + jj * 256 + tid] = Wi[r2 * NH + jj * 256 + tid];
    }
}

// ---------------------------------------------------------------------------
// Per-batch init: c[b][j] = sum_o xi_o[b][o]*Wf[o][j];  u0 = 0;
// r0[b][j] = tanh(0) + xi_h[b][j] = xi_h[b][j]
// ---------------------------------------------------------------------------
__global__ __launch_bounds__(256) void init_state(
    const float* __restrict__ Wf, const float* __restrict__ xi_o,
    const float* __restrict__ xi_h,
    float* __restrict__ c, float* __restrict__ u0, float* __restrict__ r0)
{
    __shared__ float xo_s[NOUT];
    const int b = blockIdx.x;
    const int tid = threadIdx.x;
    xo_s[tid] = xi_o[b * NOUT + tid];
    __syncthreads();
    float acc[4] = {0.f, 0.f, 0.f, 0.f};
    for (int o = 0; o < NOUT; ++o) {
        const float x = xo_s[o];
#pragma unroll
        for (int jj = 0; jj < 4; ++jj)
            acc[jj] = fmaf(x, Wf[o * NH + jj * 256 + tid], acc[jj]);
    }
#pragma unroll
    for (int jj = 0; jj < 4; ++jj) {
        const int j = jj * 256 + tid;
        c[b * NH + j]  = acc[jj];
        u0[b * NH + j] = 0.f;
        r0[b * NH + j] = xi_h[b * NH + j];
    }
}

// ---------------------------------------------------------------------------
// One timestep. Grid = 160 blocks x 256 threads.
//   blocks [0,128): du-part.  bg = blk>>5 (8 batches), jt = blk&31 (32 cols)
//     du[b][j] = dot([r|x][b][:1280], Wcomb[:,j]);  u_new = 0.9u + 0.1(du + c)
//     r_new = tanh(u_new) + xi_h
//   blocks [128,160): z-part.  z[b][o] = dot(r[b], Wo[:,o]) + xi_o -> out[b][t][o]
// K split 8 ways across threads (ks = tid>>5), LDS reduction.
// ---------------------------------------------------------------------------
__global__ __launch_bounds__(256) void step_kernel(
    int t,
    const float* __restrict__ x_all,   // [NB][NT][NFIN]
    const float* __restrict__ Wcomb,   // [1280][1024]
    const float* __restrict__ Wo,      // [1024][256]
    const float* __restrict__ c,       // [NB][NH]
    const float* __restrict__ xi_h,    // [NB][NH]
    const float* __restrict__ xi_o,    // [NB][NOUT]
    const float* __restrict__ r_in, float* __restrict__ r_out,
    const float* __restrict__ u_in, float* __restrict__ u_out,
    float* __restrict__ out)           // [NB][NT][NOUT]
{
    __shared__ __align__(16) float A_s[8 * ASTR];   // [r|x] for 8 batches
    __shared__ float part_s[8 * 256];               // K-split partials

    const int tid = threadIdx.x;
    const int jl  = tid & 31;   // column within tile
    const int ks  = tid >> 5;   // K-split index (0..7)

    const bool is_du = (blockIdx.x < 128);
    int b0, j0, klen, wld;
    const float* W;
    if (is_du) {
        b0 = (blockIdx.x >> 5) * 8;
        j0 = (blockIdx.x & 31) * 32;
        klen = KCOMB; W = Wcomb; wld = NH;
    } else {
        const int idx = blockIdx.x - 128;
        b0 = (idx >> 3) * 8;
        j0 = (idx & 7) * 32;
        klen = NH; W = Wo; wld = NOUT;
    }

    // Stage A = [r | x] for 8 batch rows into LDS (coalesced).
    for (int idx = tid; idx < 8 * NH; idx += 256) {
        const int bl = idx >> 10, k = idx & (NH - 1);
        A_s[bl * ASTR + k] = r_in[(b0 + bl) * NH + k];
    }
    if (is_du) {
        for (int idx = tid; idx < 8 * NFIN; idx += 256) {
            const int bl = idx >> 8, k = idx & (NFIN - 1);
            A_s[bl * ASTR + NH + k] =
                x_all[((size_t)(b0 + bl) * NT + t) * NFIN + k];
        }
    }
    __syncthreads();

    const int kslice = klen >> 3;         // 160 (du) or 128 (z), both %4==0
    const int kbeg   = ks * kslice;
    const float* Wp  = W + (size_t)kbeg * wld + j0 + jl;

    float acc[8] = {0.f, 0.f, 0.f, 0.f, 0.f, 0.f, 0.f, 0.f};
    for (int k = kbeg; k < kbeg + kslice; k += 4) {
        const float w0 = Wp[0];
        const float w1 = Wp[wld];
        const float w2 = Wp[2 * wld];
        const float w3 = Wp[3 * wld];
        Wp += 4 * wld;
#pragma unroll
        for (int bl = 0; bl < 8; ++bl) {
            const float4 a = *(const float4*)&A_s[bl * ASTR + k];
            float s = acc[bl];
            s = fmaf(a.x, w0, s);
            s = fmaf(a.y, w1, s);
            s = fmaf(a.z, w2, s);
            s = fmaf(a.w, w3, s);
            acc[bl] = s;
        }
    }

    // Partials: slot layout out_id = bl*32 + jl (stores conflict-free over jl)
#pragma unroll
    for (int bl = 0; bl < 8; ++bl)
        part_s[ks * 256 + bl * 32 + jl] = acc[bl];
    __syncthreads();

    float sum = 0.f;
#pragma unroll
    for (int k2 = 0; k2 < 8; ++k2)
        sum += part_s[k2 * 256 + tid];

    const int bl = tid >> 5, jo = tid & 31;
    const int b  = b0 + bl;
    if (is_du) {
        const int j = j0 + jo;
        const float du = sum + c[b * NH + j];
        const float un = 0.9f * u_in[b * NH + j] + 0.1f * du;
        u_out[b * NH + j] = un;
        r_out[b * NH + j] = tanhf(un) + xi_h[b * NH + j];
    } else {
        const int o = j0 + jo;
        out[((size_t)b * NT + t) * NOUT + o] = sum + xi_o[b * NOUT + o];
    }
}

// ---------------------------------------------------------------------------
extern "C" void kernel_launch(void* const* d_in, const int* in_sizes, int n_in,
                              void* d_out, int out_size, void* d_ws, size_t ws_size,
                              hipStream_t stream)
{
    const float* inputs = (const float*)d_in[0];  // [32,2000,256]
    const float* Wr     = (const float*)d_in[1];  // [1024,1024]
    const float* Wi     = (const float*)d_in[2];  // [256,1024]
    const float* Wf     = (const float*)d_in[3];  // [256,1024]
    const float* Wo     = (const float*)d_in[4];  // [1024,256]
    const float* xi_h   = (const float*)d_in[5];  // [32,1024]
    const float* xi_o   = (const float*)d_in[6];  // [32,256]
    float* out = (float*)d_out;

    float* ws    = (float*)d_ws;
    float* Wcomb = ws;                       // 1280*1024
    float* c     = Wcomb + KCOMB * NH;       // 32*1024
    float* u0    = c  + NB * NH;
    float* u1    = u0 + NB * NH;
    float* r0    = u1 + NB * NH;
    float* r1    = r0 + NB * NH;

    init_wcomb<<<KCOMB, 256, 0, stream>>>(Wr, Wi, Wf, Wo, Wcomb);
    init_state<<<NB, 256, 0, stream>>>(Wf, xi_o, xi_h, c, u0, r0);

    float* ub[2] = {u0, u1};
    float* rb[2] = {r0, r1};
    for (int t = 0; t < NT; ++t) {
        step_kernel<<<160, 256, 0, stream>>>(
            t, inputs, Wcomb, Wo, c, xi_h, xi_o,
            rb[t & 1], rb[(t + 1) & 1], ub[t & 1], ub[(t + 1) & 1], out);
    }
}